// Round 1
// baseline (197.371 us; speedup 1.0000x reference)
//
#include <hip/hip_runtime.h>
#include <math.h>

#define B 32
#define C 8
#define T 512
#define NSH 5
#define NCLS 10
#define NFEAT 160   // 4 groups * 5 * 8

// d_out layout (f32): out[320] | dists[5120] | probs[5120] | loss[1]
#define OUT_OFF    0
#define DIST_OFF   (B * NCLS)                 // 320
#define PROB_OFF   (DIST_OFF + B * NFEAT)     // 320 + 5120
#define LOSS_OFF   (PROB_OFF + B * NFEAT)     // 10560

__global__ __launch_bounds__(256) void shapelet_kernel(
    const float* __restrict__ x,
    const float* __restrict__ w0, const float* __restrict__ w1,
    const float* __restrict__ w2, const float* __restrict__ w3,
    const float* __restrict__ p0, const float* __restrict__ p1,
    const float* __restrict__ p2, const float* __restrict__ p3,
    float* __restrict__ out)
{
    const int bc  = blockIdx.x;          // 0..255 = b*8 + c
    const int g   = blockIdx.y;          // 0..3
    const int b   = bc >> 3;
    const int c   = bc & 7;
    const int tid = threadIdx.x;

    const float* wptr; const float* pptr; int L, M, goff;
    switch (g) {
        case 0:  wptr = w0; pptr = p0; L = 52;  M = 461; goff = 0;   break;
        case 1:  wptr = w1; pptr = p1; L = 103; M = 410; goff = 40;  break;
        case 2:  wptr = w2; pptr = p2; L = 154; M = 359; goff = 80;  break;
        default: wptr = w3; pptr = p3; L = 256; M = 257; goff = 120; break;
    }

    __shared__ float xs[T];           // normalized x row
    __shared__ float ws[NSH * 256];   // w[:, c, :] packed [n*L + j]
    __shared__ float pm[464];         // pcm[c, :]
    __shared__ float wred[8];         // cross-wave reduction scratch

    // ---- load x row, compute mean/std (ddof=1), normalize into LDS ----
    const float v0 = x[bc * T + tid];
    const float v1 = x[bc * T + tid + 256];
    float s = v0 + v1;
    #pragma unroll
    for (int off = 32; off; off >>= 1) s += __shfl_down(s, off);
    if ((tid & 63) == 0) wred[tid >> 6] = s;
    __syncthreads();
    const float mu = (wred[0] + wred[1] + wred[2] + wred[3]) * (1.0f / T);
    __syncthreads();   // wred reuse

    const float d0 = v0 - mu, d1 = v1 - mu;
    float sq = d0 * d0 + d1 * d1;
    #pragma unroll
    for (int off = 32; off; off >>= 1) sq += __shfl_down(sq, off);
    if ((tid & 63) == 0) wred[tid >> 6] = sq;
    __syncthreads();
    const float var = (wred[0] + wred[1] + wred[2] + wred[3]) * (1.0f / (T - 1));
    const float inv = 1.0f / (sqrtf(var) + 1e-8f);
    xs[tid]       = d0 * inv;
    xs[tid + 256] = d1 * inv;

    // ---- stage w (all n for this c) and pcm row ----
    for (int i = tid; i < NSH * L; i += 256) {
        const int n = i / L, j = i - n * L;
        ws[i] = wptr[(n * C + c) * L + j];
    }
    for (int i = tid; i < M; i += 256) pm[i] = pptr[c * M + i];
    __syncthreads();

    const float invL = 1.0f / (float)L;
    float* dists = out + DIST_OFF + b * NFEAT;
    float* probs = out + PROB_OFF + b * NFEAT;

    for (int n = 0; n < NSH; ++n) {
        float mind  = INFINITY;
        float mind2 = INFINITY;
        const float* wn = ws + n * L;
        for (int mm = tid; mm < M; mm += 256) {
            float acc = 0.0f;
            const float* xp = xs + mm;
            #pragma unroll 4
            for (int j = 0; j < L; ++j) acc += fabsf(xp[j] - wn[j]);
            const float d = acc * invL * pm[mm];
            mind  = fminf(mind, d);
            mind2 = fminf(mind2, d * d);
        }
        #pragma unroll
        for (int off = 32; off; off >>= 1) {
            mind  = fminf(mind,  __shfl_down(mind,  off));
            mind2 = fminf(mind2, __shfl_down(mind2, off));
        }
        __syncthreads();   // protect wred reuse across n iterations
        if ((tid & 63) == 0) { wred[tid >> 6] = mind; wred[4 + (tid >> 6)] = mind2; }
        __syncthreads();
        if (tid == 0) {
            const float md  = fminf(fminf(wred[0], wred[1]), fminf(wred[2], wred[3]));
            const float md2 = fminf(fminf(wred[4], wred[5]), fminf(wred[6], wred[7]));
            const int col = goff + n * C + c;
            dists[col] = md;
            probs[col] = expf(-md2);
        }
    }
}

__global__ __launch_bounds__(256) void head_kernel(
    const float* __restrict__ Wout,
    const float* __restrict__ w0, const float* __restrict__ w1,
    const float* __restrict__ w2, const float* __restrict__ w3,
    float* __restrict__ out)
{
    const int tid = threadIdx.x;
    if (blockIdx.x == 0) {
        // out = probs @ Wout^T : (32,160)x(10,160)^T
        const float* probs = out + PROB_OFF;
        for (int i = tid; i < B * NCLS; i += 256) {
            const int b = i / NCLS, k = i - b * NCLS;
            const float* pr = probs + b * NFEAT;
            const float* wr = Wout + k * NFEAT;
            float acc = 0.0f;
            #pragma unroll 8
            for (int f = 0; f < NFEAT; ++f) acc += pr[f] * wr[f];
            out[OUT_OFF + i] = acc;
        }
    } else {
        // loss = 0.1*mean|Wout| + 0.1*sum_g mean(exp(-dist)*mask)
        float reg = 0.0f;
        for (int i = tid; i < NCLS * NFEAT; i += 256) reg += fabsf(Wout[i]);

        const float* wptrs[4] = { w0, w1, w2, w3 };
        const int    Ls[4]    = { 52, 103, 154, 256 };
        float div = 0.0f;
        // 4 groups * 8 c * 20 ordered pairs (i!=j) = 640 tasks
        for (int task = tid; task < 640; task += 256) {
            const int g  = task / 160;
            const int r  = task - g * 160;
            const int c  = r / 20;
            const int pr = r - c * 20;
            const int i  = pr / 4;
            const int j0 = pr - i * 4;
            const int j  = j0 + (j0 >= i ? 1 : 0);
            const float* wp = wptrs[g];
            const int L = Ls[g];
            const float* wi = wp + (i * C + c) * L;
            const float* wj = wp + (j * C + c) * L;
            float ss = 0.0f;
            for (int t2 = 0; t2 < L; ++t2) {
                const float df = wj[t2] - wi[t2] + 1e-6f;
                ss += df * df;
            }
            div += expf(-sqrtf(ss));
        }

        __shared__ float r1[4], r2[4];
        #pragma unroll
        for (int off = 32; off; off >>= 1) {
            reg += __shfl_down(reg, off);
            div += __shfl_down(div, off);
        }
        if ((tid & 63) == 0) { r1[tid >> 6] = reg; r2[tid >> 6] = div; }
        __syncthreads();
        if (tid == 0) {
            const float rt = r1[0] + r1[1] + r1[2] + r1[3];
            const float dt = r2[0] + r2[1] + r2[2] + r2[3];
            out[LOSS_OFF] = 0.1f * (rt / (float)(NCLS * NFEAT)) + 0.1f * (dt / 200.0f);
        }
    }
}

extern "C" void kernel_launch(void* const* d_in, const int* in_sizes, int n_in,
                              void* d_out, int out_size, void* d_ws, size_t ws_size,
                              hipStream_t stream) {
    // setup_inputs() dict order: x, w0, pcm0, w1, pcm1, w2, pcm2, w3, pcm3, W_out
    const float* x    = (const float*)d_in[0];
    const float* w0   = (const float*)d_in[1];
    const float* pcm0 = (const float*)d_in[2];
    const float* w1   = (const float*)d_in[3];
    const float* pcm1 = (const float*)d_in[4];
    const float* w2   = (const float*)d_in[5];
    const float* pcm2 = (const float*)d_in[6];
    const float* w3   = (const float*)d_in[7];
    const float* pcm3 = (const float*)d_in[8];
    const float* Wout = (const float*)d_in[9];
    float* out = (float*)d_out;

    shapelet_kernel<<<dim3(256, 4), 256, 0, stream>>>(
        x, w0, w1, w2, w3, pcm0, pcm1, pcm2, pcm3, out);
    head_kernel<<<2, 256, 0, stream>>>(Wout, w0, w1, w2, w3, out);
}

// Round 2
// 123.700 us; speedup vs baseline: 1.5956x; 1.5956x over previous
//
#include <hip/hip_runtime.h>
#include <math.h>

#define B 32
#define C 8
#define T 512
#define NSH 5
#define NCLS 10
#define NFEAT 160   // 4 groups * 5 * 8

// d_out layout (f32): out[320] | dists[5120] | probs[5120] | loss[1]
#define OUT_OFF    0
#define DIST_OFF   (B * NCLS)                 // 320
#define PROB_OFF   (DIST_OFF + B * NFEAT)     // 5440
#define LOSS_OFF   (PROB_OFF + B * NFEAT)     // 10560

// d_ws layout (f32): div partials [0..159], reg partials [160..167]

__global__ __launch_bounds__(256) void shapelet_kernel(
    const float* __restrict__ x,
    const float* __restrict__ w0, const float* __restrict__ w1,
    const float* __restrict__ w2, const float* __restrict__ w3,
    const float* __restrict__ p0, const float* __restrict__ p1,
    const float* __restrict__ p2, const float* __restrict__ p3,
    const float* __restrict__ Wout,
    float* __restrict__ out, float* __restrict__ wsf)
{
    const int tid = threadIdx.x;

    // ---------------- loss row (blockIdx.y == 4) ----------------
    if (blockIdx.y == 4) {
        const int bc = blockIdx.x;
        __shared__ float part[4];
        const int wv   = tid >> 6;
        const int lane = tid & 63;
        if (bc < 160) {
            // 4 pair-tasks per block, one per wave. task = bc*4+wv in [0,640)
            const int task = bc * 4 + wv;
            const int g  = task / 160;
            const int r  = task - g * 160;
            const int c  = r / 20;
            const int pr = r - c * 20;
            const int i  = pr >> 2;
            const int j0 = pr & 3;
            const int j  = j0 + (j0 >= i ? 1 : 0);
            const float* wptrs[4] = { w0, w1, w2, w3 };
            const int    Ls[4]    = { 52, 103, 154, 256 };
            const int L = Ls[g];
            const float* wi = wptrs[g] + (i * C + c) * L;
            const float* wj = wptrs[g] + (j * C + c) * L;
            float ss = 0.0f;
            for (int t2 = lane; t2 < L; t2 += 64) {
                const float df = wj[t2] - wi[t2] + 1e-6f;
                ss += df * df;
            }
            #pragma unroll
            for (int off = 32; off; off >>= 1) ss += __shfl_down(ss, off);
            if (lane == 0) part[wv] = expf(-sqrtf(ss));
            __syncthreads();
            if (tid == 0) wsf[bc] = part[0] + part[1] + part[2] + part[3];
        } else if (bc < 168) {
            // L1 reg over W_out: 8 blocks x 200 elems
            float rg = 0.0f;
            if (tid < 200) rg = fabsf(Wout[(bc - 160) * 200 + tid]);
            #pragma unroll
            for (int off = 32; off; off >>= 1) rg += __shfl_down(rg, off);
            if ((tid & 63) == 0) part[wv] = rg;
            __syncthreads();
            if (tid == 0) wsf[bc] = part[0] + part[1] + part[2] + part[3];
        }
        return;
    }

    // ---------------- shapelet rows (blockIdx.y == g in [0,4)) ----------------
    const int bc = blockIdx.x;           // b*8 + c
    const int g  = blockIdx.y;
    const int b  = bc >> 3;
    const int c  = bc & 7;

    const float* wptr; const float* pptr; int L, M, goff;
    switch (g) {
        case 0:  wptr = w0; pptr = p0; L = 52;  M = 461; goff = 0;   break;
        case 1:  wptr = w1; pptr = p1; L = 103; M = 410; goff = 40;  break;
        case 2:  wptr = w2; pptr = p2; L = 154; M = 359; goff = 80;  break;
        default: wptr = w3; pptr = p3; L = 256; M = 257; goff = 120; break;
    }
    const int Lp = (L + 3) & ~3;          // padded row stride (float4 aligned)

    __shared__ __align__(16) float xs[T + 4];
    __shared__ __align__(16) float ws[NSH * 256];
    __shared__ __align__(16) float pm[464];
    __shared__ float wred[8];

    // ---- load x row, mean/std (ddof=1), normalize into LDS ----
    const float v0 = x[bc * T + tid];
    const float v1 = x[bc * T + tid + 256];
    float s = v0 + v1;
    #pragma unroll
    for (int off = 32; off; off >>= 1) s += __shfl_down(s, off);
    if ((tid & 63) == 0) wred[tid >> 6] = s;
    __syncthreads();
    const float mu = (wred[0] + wred[1] + wred[2] + wred[3]) * (1.0f / T);
    __syncthreads();
    const float d0 = v0 - mu, d1 = v1 - mu;
    float sq = d0 * d0 + d1 * d1;
    #pragma unroll
    for (int off = 32; off; off >>= 1) sq += __shfl_down(sq, off);
    if ((tid & 63) == 0) wred[tid >> 6] = sq;
    __syncthreads();
    const float var = (wred[0] + wred[1] + wred[2] + wred[3]) * (1.0f / (T - 1));
    const float inv = 1.0f / (sqrtf(var) + 1e-8f);
    xs[tid]       = d0 * inv;
    xs[tid + 256] = d1 * inv;
    if (tid < 4) xs[T + tid] = 0.0f;      // pad (read by rolling window, masked)

    // ---- stage w (padded rows) and pcm row ----
    for (int i = tid; i < NSH * Lp; i += 256) {
        const int n = i / Lp, j = i - n * Lp;
        ws[i] = (j < L) ? wptr[(n * C + c) * L + j] : 0.0f;
    }
    for (int i = tid; i < 464; i += 256) pm[i] = (i < M) ? pptr[c * M + i] : 0.0f;
    __syncthreads();

    const float invL = 1.0f / (float)L;
    const int sbase = tid * 4;            // 4 consecutive m per thread
    const bool active = (sbase < M);
    float* dists = out + DIST_OFF + b * NFEAT;
    float* probs = out + PROB_OFF + b * NFEAT;

    float pm0 = 0, pm1 = 0, pm2 = 0, pm3 = 0;
    if (active) {
        const float4 pv = *(const float4*)(pm + sbase);
        pm0 = pv.x; pm1 = pv.y; pm2 = pv.z; pm3 = pv.w;
    }

    for (int n = 0; n < NSH; ++n) {
        float a0 = 0, a1 = 0, a2 = 0, a3 = 0;
        if (active) {
            const float* wn = ws + n * Lp;
            float4 cur = *(const float4*)(xs + sbase);
            int j = 0;
            for (; j + 4 <= L; j += 4) {
                const float4 nxt = *(const float4*)(xs + sbase + j + 4);
                const float4 wv  = *(const float4*)(wn + j);
                a0 += fabsf(cur.x - wv.x); a1 += fabsf(cur.y - wv.x);
                a2 += fabsf(cur.z - wv.x); a3 += fabsf(cur.w - wv.x);
                a0 += fabsf(cur.y - wv.y); a1 += fabsf(cur.z - wv.y);
                a2 += fabsf(cur.w - wv.y); a3 += fabsf(nxt.x - wv.y);
                a0 += fabsf(cur.z - wv.z); a1 += fabsf(cur.w - wv.z);
                a2 += fabsf(nxt.x - wv.z); a3 += fabsf(nxt.y - wv.z);
                a0 += fabsf(cur.w - wv.w); a1 += fabsf(nxt.x - wv.w);
                a2 += fabsf(nxt.y - wv.w); a3 += fabsf(nxt.z - wv.w);
                cur = nxt;
            }
            for (; j < L; ++j) {          // tail (L % 4 != 0)
                const float wj = wn[j];
                a0 += fabsf(xs[sbase + j]     - wj);
                a1 += fabsf(xs[sbase + j + 1] - wj);
                a2 += fabsf(xs[sbase + j + 2] - wj);
                a3 += fabsf(xs[sbase + j + 3] - wj);
            }
        }
        float mind = INFINITY, mind2 = INFINITY;
        if (active) {
            const float dd0 = a0 * invL * pm0;
            mind = dd0; mind2 = dd0 * dd0;
            if (sbase + 1 < M) { const float dd = a1 * invL * pm1; mind = fminf(mind, dd); mind2 = fminf(mind2, dd * dd); }
            if (sbase + 2 < M) { const float dd = a2 * invL * pm2; mind = fminf(mind, dd); mind2 = fminf(mind2, dd * dd); }
            if (sbase + 3 < M) { const float dd = a3 * invL * pm3; mind = fminf(mind, dd); mind2 = fminf(mind2, dd * dd); }
        }
        #pragma unroll
        for (int off = 32; off; off >>= 1) {
            mind  = fminf(mind,  __shfl_down(mind,  off));
            mind2 = fminf(mind2, __shfl_down(mind2, off));
        }
        __syncthreads();
        if ((tid & 63) == 0) { wred[tid >> 6] = mind; wred[4 + (tid >> 6)] = mind2; }
        __syncthreads();
        if (tid == 0) {
            const float md  = fminf(fminf(wred[0], wred[1]), fminf(wred[2], wred[3]));
            const float md2 = fminf(fminf(wred[4], wred[5]), fminf(wred[6], wred[7]));
            const int col = goff + n * C + c;
            dists[col] = md;
            probs[col] = expf(-md2);
        }
    }
}

__global__ __launch_bounds__(64) void head_kernel(
    const float* __restrict__ Wout,
    const float* __restrict__ wsf,
    float* __restrict__ out)
{
    const int blk  = blockIdx.x;
    const int lane = threadIdx.x;
    if (blk < B * NCLS) {
        // out[blk] = probs[b,:] . Wout[k,:]
        const int b = blk / NCLS, k = blk - b * NCLS;
        const float* pr = out + PROB_OFF + b * NFEAT;
        const float* wr = Wout + k * NFEAT;
        float acc = 0.0f;
        #pragma unroll
        for (int r = 0; r < 3; ++r) {
            const int f = lane + r * 64;
            if (f < NFEAT) acc += pr[f] * wr[f];
        }
        #pragma unroll
        for (int off = 32; off; off >>= 1) acc += __shfl_down(acc, off);
        if (lane == 0) out[OUT_OFF + blk] = acc;
    } else {
        // finalize loss from ws partials
        float dv = 0.0f, rg = 0.0f;
        #pragma unroll
        for (int r = 0; r < 3; ++r) {
            const int i = lane + r * 64;
            if (i < 160) dv += wsf[i];
            else if (i < 168) rg += wsf[i];
        }
        #pragma unroll
        for (int off = 32; off; off >>= 1) {
            dv += __shfl_down(dv, off);
            rg += __shfl_down(rg, off);
        }
        if (lane == 0)
            out[LOSS_OFF] = 0.1f * (rg * (1.0f / 1600.0f)) + 0.1f * (dv * (1.0f / 200.0f));
    }
}

extern "C" void kernel_launch(void* const* d_in, const int* in_sizes, int n_in,
                              void* d_out, int out_size, void* d_ws, size_t ws_size,
                              hipStream_t stream) {
    // setup_inputs() dict order: x, w0, pcm0, w1, pcm1, w2, pcm2, w3, pcm3, W_out
    const float* x    = (const float*)d_in[0];
    const float* w0   = (const float*)d_in[1];
    const float* pcm0 = (const float*)d_in[2];
    const float* w1   = (const float*)d_in[3];
    const float* pcm1 = (const float*)d_in[4];
    const float* w2   = (const float*)d_in[5];
    const float* pcm2 = (const float*)d_in[6];
    const float* w3   = (const float*)d_in[7];
    const float* pcm3 = (const float*)d_in[8];
    const float* Wout = (const float*)d_in[9];
    float* out = (float*)d_out;
    float* wsf = (float*)d_ws;

    shapelet_kernel<<<dim3(256, 5), 256, 0, stream>>>(
        x, w0, w1, w2, w3, pcm0, pcm1, pcm2, pcm3, Wout, out, wsf);
    head_kernel<<<B * NCLS + 1, 64, 0, stream>>>(Wout, wsf, out);
}

// Round 3
// 111.360 us; speedup vs baseline: 1.7724x; 1.1108x over previous
//
#include <hip/hip_runtime.h>
#include <math.h>

#define B 32
#define C 8
#define T 512
#define NSH 5
#define NCLS 10
#define NFEAT 160   // 4 groups * 5 * 8

// d_out layout (f32): out[320] | dists[5120] | probs[5120] | loss[1]
#define OUT_OFF    0
#define DIST_OFF   (B * NCLS)                 // 320
#define PROB_OFF   (DIST_OFF + B * NFEAT)     // 5440
#define LOSS_OFF   (PROB_OFF + B * NFEAT)     // 10560

// d_ws (f32): wsf[0..639] = pair-diversity partials, wsf[640..643] = |Wout| partials

// One wave handles one (bc, g, n) task: lane covers m = lane*8 .. lane*8+7
// via a 12-float rolling register window. No LDS, no barriers.
template<int L, int M, int GOFF>
__device__ __forceinline__ void shapelet_task(
    const float* __restrict__ x,
    const float* __restrict__ wrow,   // w + (n*C+c)*L
    const float* __restrict__ pmrow,  // pcm + c*M
    float* __restrict__ out, int bc, int n)
{
    const int lane = threadIdx.x & 63;
    const int b = bc >> 3, c = bc & 7;
    const float* xrow = x + bc * T;

    // ---- row mean / std (ddof=1), per-wave (8 elems per lane) ----
    const float4 u0 = *(const float4*)(xrow + lane * 4);
    const float4 u1 = *(const float4*)(xrow + 256 + lane * 4);
    float s = u0.x + u0.y + u0.z + u0.w + u1.x + u1.y + u1.z + u1.w;
    #pragma unroll
    for (int off = 32; off; off >>= 1) s += __shfl_down(s, off);
    const float mu = __shfl(s, 0) * (1.0f / T);
    float sq = (u0.x-mu)*(u0.x-mu) + (u0.y-mu)*(u0.y-mu) + (u0.z-mu)*(u0.z-mu) + (u0.w-mu)*(u0.w-mu)
             + (u1.x-mu)*(u1.x-mu) + (u1.y-mu)*(u1.y-mu) + (u1.z-mu)*(u1.z-mu) + (u1.w-mu)*(u1.w-mu);
    #pragma unroll
    for (int off = 32; off; off >>= 1) sq += __shfl_down(sq, off);
    const float var = __shfl(sq, 0) * (1.0f / (T - 1));
    const float ns = 1.0f / (sqrtf(var) + 1e-8f);   // xn = x*ns + nb
    const float nb = -mu * ns;

    // ---- rolling-window L1 distances, 8 m per lane ----
    const int sbase = lane * 8;
    const int sb = (sbase < M) ? sbase : 0;   // inactive lanes read lane-0 range

    float4 a  = *(const float4*)(xrow + sb);
    float4 bb = *(const float4*)(xrow + sb + 4);
    float4 cc = *(const float4*)(xrow + sb + 8);
    a.x = fmaf(a.x, ns, nb);  a.y = fmaf(a.y, ns, nb);  a.z = fmaf(a.z, ns, nb);  a.w = fmaf(a.w, ns, nb);
    bb.x = fmaf(bb.x, ns, nb); bb.y = fmaf(bb.y, ns, nb); bb.z = fmaf(bb.z, ns, nb); bb.w = fmaf(bb.w, ns, nb);
    cc.x = fmaf(cc.x, ns, nb); cc.y = fmaf(cc.y, ns, nb); cc.z = fmaf(cc.z, ns, nb); cc.w = fmaf(cc.w, ns, nb);

    float acc[8] = {0,0,0,0,0,0,0,0};
    constexpr int LC = L & ~3;

    #pragma unroll 4
    for (int j = 0; j + 4 <= L; j += 4) {
        const float wa = wrow[j], wb = wrow[j+1], wc = wrow[j+2], wd = wrow[j+3];
        acc[0]+=fabsf(a.x-wa); acc[1]+=fabsf(a.y-wa); acc[2]+=fabsf(a.z-wa); acc[3]+=fabsf(a.w-wa);
        acc[4]+=fabsf(bb.x-wa); acc[5]+=fabsf(bb.y-wa); acc[6]+=fabsf(bb.z-wa); acc[7]+=fabsf(bb.w-wa);
        acc[0]+=fabsf(a.y-wb); acc[1]+=fabsf(a.z-wb); acc[2]+=fabsf(a.w-wb); acc[3]+=fabsf(bb.x-wb);
        acc[4]+=fabsf(bb.y-wb); acc[5]+=fabsf(bb.z-wb); acc[6]+=fabsf(bb.w-wb); acc[7]+=fabsf(cc.x-wb);
        acc[0]+=fabsf(a.z-wc); acc[1]+=fabsf(a.w-wc); acc[2]+=fabsf(bb.x-wc); acc[3]+=fabsf(bb.y-wc);
        acc[4]+=fabsf(bb.z-wc); acc[5]+=fabsf(bb.w-wc); acc[6]+=fabsf(cc.x-wc); acc[7]+=fabsf(cc.y-wc);
        acc[0]+=fabsf(a.w-wd); acc[1]+=fabsf(bb.x-wd); acc[2]+=fabsf(bb.y-wd); acc[3]+=fabsf(bb.z-wd);
        acc[4]+=fabsf(bb.w-wd); acc[5]+=fabsf(cc.x-wd); acc[6]+=fabsf(cc.y-wd); acc[7]+=fabsf(cc.z-wd);
        a = bb; bb = cc;
        int nidx = sb + j + 12;
        nidx = (nidx > T - 4) ? (T - 4) : nidx;   // clamp: garbage only feeds masked m
        cc = *(const float4*)(xrow + nidx);
        cc.x = fmaf(cc.x, ns, nb); cc.y = fmaf(cc.y, ns, nb);
        cc.z = fmaf(cc.z, ns, nb); cc.w = fmaf(cc.w, ns, nb);
    }

    if constexpr ((L & 3) != 0) {   // tail j = LC..L-1, window holds rel [LC..LC+11]
        const float rr[12] = {a.x,a.y,a.z,a.w, bb.x,bb.y,bb.z,bb.w, cc.x,cc.y,cc.z,cc.w};
        #pragma unroll
        for (int jt = 0; jt < (L & 3); ++jt) {
            const float wj = wrow[LC + jt];
            #pragma unroll
            for (int k = 0; k < 8; ++k) acc[k] += fabsf(rr[jt + k] - wj);
        }
    }

    // ---- per-lane masked min, wave reduce, write ----
    constexpr float invL = 1.0f / (float)L;
    float mind = INFINITY, mind2 = INFINITY;
    #pragma unroll
    for (int k = 0; k < 8; ++k) {
        const int m = sbase + k;
        if (m < M) {
            const float d = acc[k] * invL * pmrow[m];
            mind  = fminf(mind, d);
            mind2 = fminf(mind2, d * d);
        }
    }
    #pragma unroll
    for (int off = 32; off; off >>= 1) {
        mind  = fminf(mind,  __shfl_down(mind,  off));
        mind2 = fminf(mind2, __shfl_down(mind2, off));
    }
    if (lane == 0) {
        const int col = GOFF + n * C + c;
        out[DIST_OFF + b * NFEAT + col] = mind;
        out[PROB_OFF + b * NFEAT + col] = expf(-mind2);
    }
}

__global__ __launch_bounds__(256) void shapelet_kernel(
    const float* __restrict__ x,
    const float* __restrict__ w0, const float* __restrict__ w1,
    const float* __restrict__ w2, const float* __restrict__ w3,
    const float* __restrict__ p0, const float* __restrict__ p1,
    const float* __restrict__ p2, const float* __restrict__ p3,
    const float* __restrict__ Wout,
    float* __restrict__ out, float* __restrict__ wsf)
{
    const int blk = blockIdx.x;
    const int wv  = __builtin_amdgcn_readfirstlane(threadIdx.x >> 6);

    if (blk < 1280) {
        // task = bc*20 + gn; block's 4 waves share bc (20 % 4 == 0)
        const int bc = blk / 5;
        const int gn = (blk - bc * 5) * 4 + wv;   // 0..19
        const int g  = gn / 5;
        const int n  = gn - g * 5;
        const int c  = bc & 7;
        switch (g) {
            case 0: shapelet_task< 52, 461,   0>(x, w0 + (n*C+c)*52,  p0 + c*461, out, bc, n); break;
            case 1: shapelet_task<103, 410,  40>(x, w1 + (n*C+c)*103, p1 + c*410, out, bc, n); break;
            case 2: shapelet_task<154, 359,  80>(x, w2 + (n*C+c)*154, p2 + c*359, out, bc, n); break;
            default:shapelet_task<256, 257, 120>(x, w3 + (n*C+c)*256, p3 + c*257, out, bc, n); break;
        }
    } else if (blk < 1440) {
        // diversity pair partials: one pair per wave
        const int task = (blk - 1280) * 4 + wv;   // 0..639
        const int lane = threadIdx.x & 63;
        const int g  = task / 160;
        const int r  = task - g * 160;
        const int c  = r / 20;
        const int pr = r - c * 20;
        const int i  = pr >> 2;
        const int j0 = pr & 3;
        const int j  = j0 + (j0 >= i ? 1 : 0);
        const float* wptrs[4] = { w0, w1, w2, w3 };
        const int    Ls[4]    = { 52, 103, 154, 256 };
        const int L = Ls[g];
        const float* wi = wptrs[g] + (i * C + c) * L;
        const float* wj = wptrs[g] + (j * C + c) * L;
        float ss = 0.0f;
        for (int t2 = lane; t2 < L; t2 += 64) {
            const float df = wj[t2] - wi[t2] + 1e-6f;
            ss += df * df;
        }
        #pragma unroll
        for (int off = 32; off; off >>= 1) ss += __shfl_down(ss, off);
        if (lane == 0) wsf[task] = expf(-sqrtf(ss));
    } else {
        // |Wout| partials: wave wv sums elements [wv*400, wv*400+400)
        const int lane = threadIdx.x & 63;
        float rg = 0.0f;
        #pragma unroll
        for (int k2 = 0; k2 < 7; ++k2) {
            const int e = lane + k2 * 64;
            if (e < 400) rg += fabsf(Wout[wv * 400 + e]);
        }
        #pragma unroll
        for (int off = 32; off; off >>= 1) rg += __shfl_down(rg, off);
        if (lane == 0) wsf[640 + wv] = rg;
    }
}

__global__ __launch_bounds__(64) void head_kernel(
    const float* __restrict__ Wout,
    const float* __restrict__ wsf,
    float* __restrict__ out)
{
    const int blk  = blockIdx.x;
    const int lane = threadIdx.x;
    if (blk < B * NCLS) {
        const int b = blk / NCLS, k = blk - b * NCLS;
        const float* pr = out + PROB_OFF + b * NFEAT;
        const float* wr = Wout + k * NFEAT;
        float acc = 0.0f;
        #pragma unroll
        for (int r = 0; r < 3; ++r) {
            const int f = lane + r * 64;
            if (f < NFEAT) acc += pr[f] * wr[f];
        }
        #pragma unroll
        for (int off = 32; off; off >>= 1) acc += __shfl_down(acc, off);
        if (lane == 0) out[OUT_OFF + blk] = acc;
    } else {
        float dv = 0.0f, rg = 0.0f;
        #pragma unroll
        for (int r = 0; r < 10; ++r) {
            const int i = lane + r * 64;
            if (i < 640) dv += wsf[i];
        }
        if (lane < 4) rg = wsf[640 + lane];
        #pragma unroll
        for (int off = 32; off; off >>= 1) {
            dv += __shfl_down(dv, off);
            rg += __shfl_down(rg, off);
        }
        if (lane == 0)
            out[LOSS_OFF] = 0.1f * (rg * (1.0f / 1600.0f)) + 0.1f * (dv * (1.0f / 200.0f));
    }
}

extern "C" void kernel_launch(void* const* d_in, const int* in_sizes, int n_in,
                              void* d_out, int out_size, void* d_ws, size_t ws_size,
                              hipStream_t stream) {
    // setup_inputs() dict order: x, w0, pcm0, w1, pcm1, w2, pcm2, w3, pcm3, W_out
    const float* x    = (const float*)d_in[0];
    const float* w0   = (const float*)d_in[1];
    const float* pcm0 = (const float*)d_in[2];
    const float* w1   = (const float*)d_in[3];
    const float* pcm1 = (const float*)d_in[4];
    const float* w2   = (const float*)d_in[5];
    const float* pcm2 = (const float*)d_in[6];
    const float* w3   = (const float*)d_in[7];
    const float* pcm3 = (const float*)d_in[8];
    const float* Wout = (const float*)d_in[9];
    float* out = (float*)d_out;
    float* wsf = (float*)d_ws;

    shapelet_kernel<<<1441, 256, 0, stream>>>(
        x, w0, w1, w2, w3, pcm0, pcm1, pcm2, pcm3, Wout, out, wsf);
    head_kernel<<<B * NCLS + 1, 64, 0, stream>>>(Wout, wsf, out);
}

// Round 4
// 107.141 us; speedup vs baseline: 1.8422x; 1.0394x over previous
//
#include <hip/hip_runtime.h>
#include <math.h>

#define B 32
#define C 8
#define T 512
#define NSH 5
#define NCLS 10
#define NFEAT 160   // 4 groups * 5 * 8

// d_out layout (f32): out[320] | dists[5120] | probs[5120] | loss[1]
#define OUT_OFF    0
#define DIST_OFF   (B * NCLS)                 // 320
#define PROB_OFF   (DIST_OFF + B * NFEAT)     // 5440
#define LOSS_OFF   (PROB_OFF + B * NFEAT)     // 10560

// d_ws (f32): [0..639] div pair partials | [640..643] |Wout| partials
//             [648..1159] (ns, nb) per bc row (256 x 2)
#define MUINV_OFF 648

// ---------------------------------------------------------------------------
// prep: per-row normalization constants + loss partials
// ---------------------------------------------------------------------------
__global__ __launch_bounds__(256) void prep_kernel(
    const float* __restrict__ x,
    const float* __restrict__ w0, const float* __restrict__ w1,
    const float* __restrict__ w2, const float* __restrict__ w3,
    const float* __restrict__ Wout,
    float* __restrict__ wsf)
{
    const int blk  = blockIdx.x;
    const int wv   = __builtin_amdgcn_readfirstlane(threadIdx.x >> 6);
    const int lane = threadIdx.x & 63;

    if (blk < 64) {
        const int bc = blk * 4 + wv;
        const float* xr = x + bc * T;
        const float4 u0 = *(const float4*)(xr + lane * 4);
        const float4 u1 = *(const float4*)(xr + 256 + lane * 4);
        float s = u0.x + u0.y + u0.z + u0.w + u1.x + u1.y + u1.z + u1.w;
        #pragma unroll
        for (int off = 32; off; off >>= 1) s += __shfl_down(s, off);
        const float mu = __shfl(s, 0) * (1.0f / T);
        float sq = (u0.x-mu)*(u0.x-mu) + (u0.y-mu)*(u0.y-mu) + (u0.z-mu)*(u0.z-mu) + (u0.w-mu)*(u0.w-mu)
                 + (u1.x-mu)*(u1.x-mu) + (u1.y-mu)*(u1.y-mu) + (u1.z-mu)*(u1.z-mu) + (u1.w-mu)*(u1.w-mu);
        #pragma unroll
        for (int off = 32; off; off >>= 1) sq += __shfl_down(sq, off);
        if (lane == 0) {
            const float var = sq * (1.0f / (T - 1));
            const float ns  = 1.0f / (sqrtf(var) + 1e-8f);
            wsf[MUINV_OFF + 2*bc]     = ns;
            wsf[MUINV_OFF + 2*bc + 1] = -mu * ns;
        }
    } else if (blk < 224) {
        // diversity pair partials: one ordered pair per wave
        const int task = (blk - 64) * 4 + wv;   // 0..639
        const int g  = task / 160;
        const int r  = task - g * 160;
        const int c  = r / 20;
        const int pr = r - c * 20;
        const int i  = pr >> 2;
        const int j0 = pr & 3;
        const int j  = j0 + (j0 >= i ? 1 : 0);
        const float* wptrs[4] = { w0, w1, w2, w3 };
        const int    Ls[4]    = { 52, 103, 154, 256 };
        const int L = Ls[g];
        const float* wi = wptrs[g] + (i * C + c) * L;
        const float* wj = wptrs[g] + (j * C + c) * L;
        float ss = 0.0f;
        for (int t2 = lane; t2 < L; t2 += 64) {
            const float df = wj[t2] - wi[t2] + 1e-6f;
            ss += df * df;
        }
        #pragma unroll
        for (int off = 32; off; off >>= 1) ss += __shfl_down(ss, off);
        if (lane == 0) wsf[task] = expf(-sqrtf(ss));
    } else {
        // |Wout| partials: wave wv sums elements [wv*400, wv*400+400)
        float rg = 0.0f;
        #pragma unroll
        for (int k2 = 0; k2 < 7; ++k2) {
            const int e = lane + k2 * 64;
            if (e < 400) rg += fabsf(Wout[wv * 400 + e]);
        }
        #pragma unroll
        for (int off = 32; off; off >>= 1) rg += __shfl_down(rg, off);
        if (lane == 0) wsf[640 + wv] = rg;
    }
}

// ---------------------------------------------------------------------------
// shapelet: one wave per (bc, g, n) task. Circular 16-reg window, static
// indices, 2-phase-deep prefetch (pv0/pv1 alternate). MPL = m's per lane.
// CW = window span (12 for MPL=8 / float4 chunks; 10 for MPL=6 / float2).
// ---------------------------------------------------------------------------
template<int L, int M, int GOFF, int MPL, int CW>
__device__ __forceinline__ void shapelet_task(
    const float* __restrict__ xrow,
    const float* __restrict__ wrow,
    const float* __restrict__ pmrow,
    const float* __restrict__ minv2,
    float* __restrict__ out, int b, int c, int n)
{
    const int lane  = threadIdx.x & 63;
    const int sbase = lane * MPL;
    const int sb = (sbase < M) ? sbase : 0;

    const float ns = minv2[0];
    const float nb = minv2[1];

    float U[16];
    float acc[MPL];
    #pragma unroll
    for (int k = 0; k < MPL; ++k) acc[k] = 0.0f;

    auto LOADCHUNK = [&](int addr) -> float4 {
        int a = addr; if (a > T - 4) a = T - 4;
        if constexpr (CW == 12) {
            return *(const float4*)(xrow + a);
        } else {
            const float2 lo = *(const float2*)(xrow + a);
            const float2 hi = *(const float2*)(xrow + a + 2);
            return float4{lo.x, lo.y, hi.x, hi.y};
        }
    };

    // initial window fill: positions [0 .. CW-1]  (sb+CW-1 <= 467 < T)
    if constexpr (CW == 12) {
        #pragma unroll
        for (int q = 0; q < 3; ++q) {
            const float4 v = *(const float4*)(xrow + sb + q * 4);
            U[q*4+0] = fmaf(v.x, ns, nb); U[q*4+1] = fmaf(v.y, ns, nb);
            U[q*4+2] = fmaf(v.z, ns, nb); U[q*4+3] = fmaf(v.w, ns, nb);
        }
    } else {
        #pragma unroll
        for (int q = 0; q < 5; ++q) {
            const float2 v = *(const float2*)(xrow + sb + q * 2);
            U[q*2+0] = fmaf(v.x, ns, nb); U[q*2+1] = fmaf(v.y, ns, nb);
        }
    }
    float4 pv0 = LOADCHUNK(sb + CW);        // committed at phase 0
    float4 pv1 = LOADCHUNK(sb + CW + 4);    // committed at phase 1

    int j = 0;

#define PHASE(BB, PV)                                                      \
    {                                                                      \
        U[(BB + CW + 0) & 15] = fmaf(PV.x, ns, nb);                        \
        U[(BB + CW + 1) & 15] = fmaf(PV.y, ns, nb);                        \
        U[(BB + CW + 2) & 15] = fmaf(PV.z, ns, nb);                        \
        U[(BB + CW + 3) & 15] = fmaf(PV.w, ns, nb);                        \
        PV = LOADCHUNK(sb + j + CW + 8);                                   \
        _Pragma("unroll")                                                  \
        for (int jj = 0; jj < 4; ++jj) {                                   \
            const float wj = wrow[j + jj];                                 \
            _Pragma("unroll")                                              \
            for (int k = 0; k < MPL; ++k)                                  \
                acc[k] += fabsf(U[(BB + jj + k) & 15] - wj);               \
        }                                                                  \
        j += 4;                                                            \
    }

    constexpr int NP    = L / 4;     // full 4-j phases
    constexpr int NLOOP = NP / 4;
    constexpr int NTAIL = NP % 4;
    for (int it = 0; it < NLOOP; ++it) {
        PHASE(0,  pv0)
        PHASE(4,  pv1)
        PHASE(8,  pv0)
        PHASE(12, pv1)
    }
    if constexpr (NTAIL >= 1) PHASE(0, pv0)
    if constexpr (NTAIL >= 2) PHASE(4, pv1)
    if constexpr (NTAIL >= 3) PHASE(8, pv0)
#undef PHASE

    if constexpr ((L & 3) != 0) {        // scalar tail, window still valid
        constexpr int TB = (4 * NP) & 15;
        #pragma unroll
        for (int jt = 0; jt < (L & 3); ++jt) {
            const float wj = wrow[4 * NP + jt];
            #pragma unroll
            for (int k = 0; k < MPL; ++k)
                acc[k] += fabsf(U[(TB + jt + k) & 15] - wj);
        }
    }

    constexpr float invL = 1.0f / (float)L;
    float mind = INFINITY, mind2 = INFINITY;
    #pragma unroll
    for (int k = 0; k < MPL; ++k) {
        const int m = sbase + k;
        if (m < M) {
            const float d = acc[k] * invL * pmrow[m];
            mind  = fminf(mind, d);
            mind2 = fminf(mind2, d * d);
        }
    }
    #pragma unroll
    for (int off = 32; off; off >>= 1) {
        mind  = fminf(mind,  __shfl_down(mind,  off));
        mind2 = fminf(mind2, __shfl_down(mind2, off));
    }
    if (lane == 0) {
        const int col = GOFF + n * C + c;
        out[DIST_OFF + b * NFEAT + col] = mind;
        out[PROB_OFF + b * NFEAT + col] = expf(-mind2);
    }
}

__global__ __launch_bounds__(256) void shapelet_kernel(
    const float* __restrict__ x,
    const float* __restrict__ w0, const float* __restrict__ w1,
    const float* __restrict__ w2, const float* __restrict__ w3,
    const float* __restrict__ p0, const float* __restrict__ p1,
    const float* __restrict__ p2, const float* __restrict__ p3,
    float* __restrict__ out, const float* __restrict__ wsf)
{
    const int blk = blockIdx.x;
    const int wv  = __builtin_amdgcn_readfirstlane(threadIdx.x >> 6);

    // longest group (g3) dispatches first for makespan
    int gsel, base;
    if      (blk < 320) { gsel = 3; base = 0;   }
    else if (blk < 640) { gsel = 2; base = 320; }
    else if (blk < 960) { gsel = 1; base = 640; }
    else                { gsel = 0; base = 960; }

    const int lt = (blk - base) * 4 + wv;   // 0..1279
    const int bc = lt / 5;
    const int n  = lt - bc * 5;
    const int c  = bc & 7;
    const int b  = bc >> 3;
    const float* xr = x + bc * T;
    const float* mi = wsf + MUINV_OFF + 2 * bc;

    switch (gsel) {
        case 3:  shapelet_task<256, 257, 120, 6, 10>(xr, w3 + (n*C+c)*256, p3 + c*257, mi, out, b, c, n); break;
        case 2:  shapelet_task<154, 359,  80, 6, 10>(xr, w2 + (n*C+c)*154, p2 + c*359, mi, out, b, c, n); break;
        case 1:  shapelet_task<103, 410,  40, 8, 12>(xr, w1 + (n*C+c)*103, p1 + c*410, mi, out, b, c, n); break;
        default: shapelet_task< 52, 461,   0, 8, 12>(xr, w0 + (n*C+c)*52,  p0 + c*461, mi, out, b, c, n); break;
    }
}

// ---------------------------------------------------------------------------
// head: GEMV + loss finalize
// ---------------------------------------------------------------------------
__global__ __launch_bounds__(64) void head_kernel(
    const float* __restrict__ Wout,
    const float* __restrict__ wsf,
    float* __restrict__ out)
{
    const int blk  = blockIdx.x;
    const int lane = threadIdx.x;
    if (blk < B * NCLS) {
        const int b = blk / NCLS, k = blk - b * NCLS;
        const float* pr = out + PROB_OFF + b * NFEAT;
        const float* wr = Wout + k * NFEAT;
        float acc = 0.0f;
        #pragma unroll
        for (int r = 0; r < 3; ++r) {
            const int f = lane + r * 64;
            if (f < NFEAT) acc += pr[f] * wr[f];
        }
        #pragma unroll
        for (int off = 32; off; off >>= 1) acc += __shfl_down(acc, off);
        if (lane == 0) out[OUT_OFF + blk] = acc;
    } else {
        float dv = 0.0f, rg = 0.0f;
        #pragma unroll
        for (int r = 0; r < 10; ++r) {
            const int i = lane + r * 64;
            if (i < 640) dv += wsf[i];
        }
        if (lane < 4) rg = wsf[640 + lane];
        #pragma unroll
        for (int off = 32; off; off >>= 1) {
            dv += __shfl_down(dv, off);
            rg += __shfl_down(rg, off);
        }
        if (lane == 0)
            out[LOSS_OFF] = 0.1f * (rg * (1.0f / 1600.0f)) + 0.1f * (dv * (1.0f / 200.0f));
    }
}

extern "C" void kernel_launch(void* const* d_in, const int* in_sizes, int n_in,
                              void* d_out, int out_size, void* d_ws, size_t ws_size,
                              hipStream_t stream) {
    // setup_inputs() dict order: x, w0, pcm0, w1, pcm1, w2, pcm2, w3, pcm3, W_out
    const float* x    = (const float*)d_in[0];
    const float* w0   = (const float*)d_in[1];
    const float* pcm0 = (const float*)d_in[2];
    const float* w1   = (const float*)d_in[3];
    const float* pcm1 = (const float*)d_in[4];
    const float* w2   = (const float*)d_in[5];
    const float* pcm2 = (const float*)d_in[6];
    const float* w3   = (const float*)d_in[7];
    const float* pcm3 = (const float*)d_in[8];
    const float* Wout = (const float*)d_in[9];
    float* out = (float*)d_out;
    float* wsf = (float*)d_ws;

    prep_kernel<<<225, 256, 0, stream>>>(x, w0, w1, w2, w3, Wout, wsf);
    shapelet_kernel<<<1280, 256, 0, stream>>>(
        x, w0, w1, w2, w3, pcm0, pcm1, pcm2, pcm3, out, wsf);
    head_kernel<<<B * NCLS + 1, 64, 0, stream>>>(Wout, wsf, out);
}